// Round 9
// baseline (86.237 us; speedup 1.0000x reference)
//
#include <hip/hip_runtime.h>
#include <hip/hip_bf16.h>
#include <cstdint>
#include <cstddef>

#define TOKENS 16384
#define DMODEL 4096
#define NEXP   64
#define NWAVE  4
#define WINK   256                    // k-floats per window (1KB per row)
#define NWIN   (DMODEL / WINK)        // 16 windows
#define WCH    (WINK / 16)            // 16 k16-chunks per window
#define CPW    (WCH / NWAVE)          // 4 chunks per wave per window

typedef __attribute__((ext_vector_type(8)))  short bf16x8;   // 8 bf16 = 4 VGPRs
typedef __attribute__((ext_vector_type(16))) float f32x16;   // 32x32 acc

// async global->LDS, 16B/lane; dest = wave-uniform base + lane*16 (linear)
__device__ __forceinline__ void gld_lds16(const float* g, void* l) {
  __builtin_amdgcn_global_load_lds(
      (__attribute__((address_space(1))) const void*)g,
      (__attribute__((address_space(3))) void*)l, 16, 0, 0);
}

// 8 fp32 -> hi/lo bf16 (RNE hi, exact residual -> lo; ~2^-17 rel)
__device__ __forceinline__ void cvt_hilo8(const float f[8], bf16x8* hi, bf16x8* lo) {
  union { __hip_bfloat16 b; unsigned short u; } cv;
  bf16x8 hv, lv;
#pragma unroll
  for (int j = 0; j < 8; ++j) {
    __hip_bfloat16 hb = __float2bfloat16(f[j]);
    cv.b = hb; hv[j] = (short)cv.u;
    float r = f[j] - __bfloat162float(hb);
    cv.b = __float2bfloat16(r); lv[j] = (short)cv.u;
  }
  *hi = hv; *lo = lv;
}

// ---------------- kernel 1: W -> 32x32x16 B-fragments, bf16 hi/lo (verified) ----------
// slot (kc*2+et)*64+l <- B[k=kc*16+(l>>5)*8+j][e=et*32+(l&31)] = W[e][k+j]
__global__ __launch_bounds__(256)
void prep_W(const float* __restrict__ W, uint4* __restrict__ wh, uint4* __restrict__ wl) {
  const int tid = blockIdx.x * 256 + threadIdx.x;   // 32768 threads
  const int l  = tid & 63;
  const int et = (tid >> 6) & 1;
  const int kc = tid >> 7;                           // 0..255 (global k16-chunk)
  const int e  = et * 32 + (l & 31);
  const int k  = kc * 16 + (l >> 5) * 8;
  const float* src = W + (size_t)e * DMODEL + k;
  float f[8];
#pragma unroll
  for (int j = 0; j < 8; ++j) f[j] = src[j];
  bf16x8 hi, lo;
  cvt_hilo8(f, &hi, &lo);
  const int slot = (kc * 2 + et) * 64 + l;
  wh[slot] = __builtin_bit_cast(uint4, hi);
  wl[slot] = __builtin_bit_cast(uint4, lo);
}

// ---------------- kernel 2: DMA-staged GEMM, counted-vmcnt pipeline (T3+T4) ----------
// 512 blocks x 256 thr (2/CU). Window = 32 rows x 1KB DMA'd (1KB-contiguous requests),
// double-buffered; raw s_barrier + s_waitcnt vmcnt(24) — prefetch DMAs NEVER drained.
// Invariant (in-order vmcnt): W(wi) issued before D(wi+1), so at head(wi) the 24 newest
// outstanding = {W(wi)[16], D(wi+1)[8]} and vmcnt(24) completes exactly D(wi) and older.
__global__ __launch_bounds__(256, 2)
void gemm_topk(const float* __restrict__ x, const uint4* __restrict__ whB,
               const uint4* __restrict__ wlB, const float* __restrict__ b,
               float* __restrict__ out) {
  __shared__ __align__(16) char lds[65536];   // [xb0 32K][xb1 32K]
  const int tid = threadIdx.x;
  const int l   = tid & 63;
  const int w   = tid >> 6;
  const int t0  = blockIdx.x * 32;
  const int row = l & 31, g = l >> 5;

  char* xb0 = lds;
  char* xb1 = lds + 32768;
  const uint4* whp = whB + l;
  const uint4* wlp = wlB + l;

  // stage window win: wave w instr p -> row p*4+w, one 1KB contiguous run (lane-permuted)
  // Stored 16B-unit s of row r holds global unit s ^ (r&7); reads apply the same XOR.
  auto stage = [&](int win, char* buf) {
#pragma unroll
    for (int p = 0; p < 8; ++p) {
      const int r  = p * 4 + w;
      const int sb = (l * 16) ^ ((r & 7) << 4);          // swizzled source byte in [0,1024)
      const float* src = x + (size_t)(t0 + r) * DMODEL + win * WINK + (sb >> 2);
      gld_lds16(src, buf + p * 4096 + tid * 16);
    }
  };

  // W for one window, preloaded to regs (single-buffered; compute is VMEM-free)
  uint4 bh0[4], bh1[4], bl0[4], bl1[4];
  auto wload = [&](int win) {
#pragma unroll
    for (int c = 0; c < 4; ++c) {
      const size_t base = (size_t)(win * WCH + w * CPW + c) * 128;
      bh0[c] = whp[base];      bh1[c] = whp[base + 64];
      bl0[c] = wlp[base];      bl1[c] = wlp[base + 64];
    }
  };

  f32x16 acc0, acc1;
#pragma unroll
  for (int i = 0; i < 16; ++i) { acc0[i] = 0.f; acc1[i] = 0.f; }

  auto compute = [&](const char* buf) {
#pragma unroll
    for (int c = 0; c < 4; ++c) {
      const int u  = (w * CPW + c) * 4 + g * 2;          // window-local 16B-unit
      const int sw = (row & 7);
      float4 a0 = *(const float4*)(buf + row * 1024 + ((u ^ sw) << 4));
      float4 a1 = *(const float4*)(buf + row * 1024 + (((u + 1) ^ sw) << 4));
      float f[8] = {a0.x, a0.y, a0.z, a0.w, a1.x, a1.y, a1.z, a1.w};
      bf16x8 ah, al;
      cvt_hilo8(f, &ah, &al);
      bf16x8 vh0 = __builtin_bit_cast(bf16x8, bh0[c]);
      bf16x8 vh1 = __builtin_bit_cast(bf16x8, bh1[c]);
      bf16x8 vl0 = __builtin_bit_cast(bf16x8, bl0[c]);
      bf16x8 vl1 = __builtin_bit_cast(bf16x8, bl1[c]);
      // fp32-emulated: hi*hi + hi*lo + lo*hi
      acc0 = __builtin_amdgcn_mfma_f32_32x32x16_bf16(ah, vh0, acc0, 0, 0, 0);
      acc1 = __builtin_amdgcn_mfma_f32_32x32x16_bf16(ah, vh1, acc1, 0, 0, 0);
      acc0 = __builtin_amdgcn_mfma_f32_32x32x16_bf16(ah, vl0, acc0, 0, 0, 0);
      acc1 = __builtin_amdgcn_mfma_f32_32x32x16_bf16(ah, vl1, acc1, 0, 0, 0);
      acc0 = __builtin_amdgcn_mfma_f32_32x32x16_bf16(al, vh0, acc0, 0, 0, 0);
      acc1 = __builtin_amdgcn_mfma_f32_32x32x16_bf16(al, vh1, acc1, 0, 0, 0);
    }
  };

  // prologue — order pinned: D0, W0, D1  (W0 older than D1)
  stage(0, xb0);
  __builtin_amdgcn_sched_barrier(0);
  wload(0);
  __builtin_amdgcn_sched_barrier(0);
  stage(1, xb1);
  __builtin_amdgcn_sched_barrier(0);

  for (int wi = 0; wi < NWIN; ++wi) {
    char* buf = (wi & 1) ? xb1 : xb0;
    // head: complete my D(wi) (and older) without draining W(wi)/D(wi+1)
    if (wi == NWIN - 1) asm volatile("s_waitcnt vmcnt(16)" ::: "memory");
    else                asm volatile("s_waitcnt vmcnt(24)" ::: "memory");
    __builtin_amdgcn_sched_barrier(0);
    __builtin_amdgcn_s_barrier();                // all waves' D(wi) complete
    __builtin_amdgcn_sched_barrier(0);
    compute(buf);                                // VMEM-free: LDS + MFMA only
    __builtin_amdgcn_sched_barrier(0);
    __builtin_amdgcn_s_barrier();                // buf consumed by all waves
    __builtin_amdgcn_sched_barrier(0);
    if (wi + 1 < NWIN) { wload(wi + 1); __builtin_amdgcn_sched_barrier(0); }
    if (wi + 2 < NWIN) { stage(wi + 2, buf); __builtin_amdgcn_sched_barrier(0); }
  }
  __syncthreads();                               // nothing left outstanding

  // ---- epilogue (verbatim R4/R8, verified): K-split reduce + bias + top-2 + softmax ----
  // C/D 32x32 layout: expert col = lane&31, token row rr = (r&3)+8*(r>>2)+4*(lane>>5)
  float* red = (float*)lds;           // [4][32*64] = 32KB, aliases xb0 (safe: post-barrier)
  {
    float* rp = red + w * (32 * NEXP);
#pragma unroll
    for (int r = 0; r < 16; ++r) {
      const int rr = (r & 3) + 8 * (r >> 2) + 4 * g;
      rp[rr * NEXP + row]      = acc0[r];
      rp[rr * NEXP + 32 + row] = acc1[r];
    }
  }
  __syncthreads();

  const float bias = b[tid & 63];
#pragma unroll
  for (int j = 0; j < 8; ++j) {
    const int f = tid + 256 * j;      // bank = tid%32, conflict-free; expert = tid&63
    float s = red[f] + red[2048 + f] + red[4096 + f] + red[6144 + f] + bias;
    red[f] = s;                       // owner-exclusive
  }
  __syncthreads();

#pragma unroll
  for (int i = 0; i < 8; ++i) {
    const int tl = w * 8 + i;
    const float v = red[tl * NEXP + l];

    float m1 = v; int i1 = l;
#pragma unroll
    for (int off = 32; off > 0; off >>= 1) {
      float ov = __shfl_xor(m1, off, 64);
      int   oi = __shfl_xor(i1, off, 64);
      if (ov > m1 || (ov == m1 && oi < i1)) { m1 = ov; i1 = oi; }
    }
    float v2 = (l == i1) ? -__builtin_inff() : v;
    float m2 = v2; int i2 = l;
#pragma unroll
    for (int off = 32; off > 0; off >>= 1) {
      float ov = __shfl_xor(m2, off, 64);
      int   oi = __shfl_xor(i2, off, 64);
      if (ov > m2 || (ov == m2 && oi < i2)) { m2 = ov; i2 = oi; }
    }
    float e = __expf(v - m1);
#pragma unroll
    for (int off = 32; off > 0; off >>= 1) e += __shfl_xor(e, off, 64);

    if (l == 0) {
      const int t = t0 + tl;
      out[(size_t)t * 2 + 0] = (float)i1;
      out[(size_t)t * 2 + 1] = (float)i2;
      float inv = 1.0f / e;
      out[(size_t)TOKENS * 2 + (size_t)t * 2 + 0] = inv;
      out[(size_t)TOKENS * 2 + (size_t)t * 2 + 1] = __expf(m2 - m1) * inv;
    }
  }
}

extern "C" void kernel_launch(void* const* d_in, const int* in_sizes, int n_in,
                              void* d_out, int out_size, void* d_ws, size_t ws_size,
                              hipStream_t stream) {
  const float* x = (const float*)d_in[0];
  const float* W = (const float*)d_in[1];
  const float* b = (const float*)d_in[2];
  float* out = (float*)d_out;

  uint4* wh = (uint4*)d_ws;          // 32768 slots * 16B = 512 KB
  uint4* wl = wh + 32768;            // 512 KB

  hipLaunchKernelGGL(prep_W,    dim3(128),         dim3(256), 0, stream, W, wh, wl);
  hipLaunchKernelGGL(gemm_topk, dim3(TOKENS / 32), dim3(256), 0, stream, x, wh, wl, b, out);
}

// Round 10
// 77.709 us; speedup vs baseline: 1.1097x; 1.1097x over previous
//
#include <hip/hip_runtime.h>
#include <hip/hip_bf16.h>
#include <cstdint>
#include <cstddef>

#define TOKENS 16384
#define DMODEL 4096
#define NEXP   64
#define NWAVE  4                      // waves per block = K-split within block
#define KSPAN  (DMODEL / NWAVE)       // 1024 k per wave
#define NKC    (KSPAN / 16)           // 64 k-chunks of 16
#define NMAC   (NKC / 4)              // 16 macro-iters (4 chunks = 256B/row burst)

typedef __attribute__((ext_vector_type(8)))  short bf16x8;   // 8 bf16 = 4 VGPRs
typedef __attribute__((ext_vector_type(16))) float f32x16;   // 32x32 acc

// 8 fp32 -> hi/lo bf16 fragments (RNE hi, exact fp32 residual -> lo; ~2^-17 rel)
__device__ __forceinline__ void cvt_hilo8(const float f[8], bf16x8* hi, bf16x8* lo) {
  union { __hip_bfloat16 b; unsigned short u; } cv;
  bf16x8 hv, lv;
#pragma unroll
  for (int j = 0; j < 8; ++j) {
    __hip_bfloat16 hb = __float2bfloat16(f[j]);
    cv.b = hb; hv[j] = (short)cv.u;
    float r = f[j] - __bfloat162float(hb);          // exact
    cv.b = __float2bfloat16(r); lv[j] = (short)cv.u;
  }
  *hi = hv; *lo = lv;
}

// ---------------- kernel 1: W -> 32x32x16 B-fragments, bf16 hi/lo (verified) ----------
// slot (kc*2+et)*64+l <- B[k=kc*16+(l>>5)*8+j][e=et*32+(l&31)] = W[e][k+j]
__global__ __launch_bounds__(256)
void prep_W(const float* __restrict__ W, uint4* __restrict__ wh, uint4* __restrict__ wl) {
  const int tid = blockIdx.x * 256 + threadIdx.x;   // 32768 threads total
  const int l  = tid & 63;
  const int et = (tid >> 6) & 1;
  const int kc = tid >> 7;                           // 0..255 (global k16-chunk)
  const int e  = et * 32 + (l & 31);
  const int k  = kc * 16 + (l >> 5) * 8;
  const float* src = W + (size_t)e * DMODEL + k;
  float f[8];
#pragma unroll
  for (int j = 0; j < 8; ++j) f[j] = src[j];
  bf16x8 hi, lo;
  cvt_hilo8(f, &hi, &lo);
  const int slot = (kc * 2 + et) * 64 + l;
  wh[slot] = __builtin_bit_cast(uint4, hi);
  wl[slot] = __builtin_bit_cast(uint4, lo);
}

// ---------------- kernel 2: R4 structure + per-block K-phase rotation ----------------
// grid 512 blocks x 256 thr (4 waves). Block = 32 tokens x 64 experts; wave w = K-quarter w.
// Block walks its 16 macros in rotated order (m + ph) & 15, ph = bid & 15, so the chip's
// instantaneous address set spreads over all 16KB-stride phases (de-camps HBM channels).
__global__ __launch_bounds__(256, 2)
void gemm_topk(const float* __restrict__ x, const uint4* __restrict__ wh,
               const uint4* __restrict__ wl, const float* __restrict__ b,
               float* __restrict__ out) {
  __shared__ float red[NWAVE][32 * NEXP];   // 32 KB

  const int tid = threadIdx.x;
  const int l   = tid & 63;
  const int w   = tid >> 6;                 // wave id = K-quarter
  const int t0  = blockIdx.x * 32;
  const int row = l & 31, g = l >> 5;
  const int ph  = blockIdx.x & 15;          // K-phase rotation

  const float* xp  = x  + (size_t)(t0 + row) * DMODEL + w * KSPAN + g * 8;
  const uint4* whp = wh + (size_t)w * (NKC * 128) + l;   // 128 uint4 per k-chunk
  const uint4* wlp = wl + (size_t)w * (NKC * 128) + l;

  // position kc (0..63) -> rotated chunk index (same low-2 bits, macro rotated by ph)
  auto rot = [&](int kc) { return ((((kc >> 2) + ph) & 15) << 2) | (kc & 3); };

  f32x16 acc0, acc1;
#pragma unroll
  for (int i = 0; i < 16; ++i) { acc0[i] = 0.f; acc1[i] = 0.f; }

  // x: depth-1 macro double-buffer (8 float4/slot); W: depth-2 chunk rotation.
  float4 xa[2][8];
  uint4  ph0[2], ph1[2], pl0[2], pl1[2];

  auto ldxm = [&](int mac, int s) {         // macro position -> rotated macro's 256B burst
    const int rm = (mac + ph) & 15;
#pragma unroll
    for (int c = 0; c < 4; ++c) {
      const float* xn = xp + (size_t)(rm * 4 + c) * 16;
      xa[s][c * 2]     = *(const float4*)(xn);
      xa[s][c * 2 + 1] = *(const float4*)(xn + 4);
    }
  };
  auto ldw = [&](int kc, int s) {           // position kc -> rotated chunk's W fragments
    const int rc = rot(kc);
    ph0[s] = whp[rc * 128];  ph1[s] = whp[rc * 128 + 64];
    pl0[s] = wlp[rc * 128];  pl1[s] = wlp[rc * 128 + 64];
  };

  auto chunk = [&](int kc, int xs, int c) { // consume position kc (rotated data pair)
    const int ws = kc & 1;
    float4 a0 = xa[xs][c * 2], a1 = xa[xs][c * 2 + 1];
    uint4 bh0 = ph0[ws], bh1 = ph1[ws], bl0 = pl0[ws], bl1 = pl1[ws];
    if (kc + 2 < NKC) ldw(kc + 2, ws);      // same parity -> same slot, freed this chunk
    float f[8] = {a0.x, a0.y, a0.z, a0.w, a1.x, a1.y, a1.z, a1.w};
    bf16x8 ah, al;
    cvt_hilo8(f, &ah, &al);
    bf16x8 vh0 = __builtin_bit_cast(bf16x8, bh0);
    bf16x8 vh1 = __builtin_bit_cast(bf16x8, bh1);
    bf16x8 vl0 = __builtin_bit_cast(bf16x8, bl0);
    bf16x8 vl1 = __builtin_bit_cast(bf16x8, bl1);
    // fp32-emulated: hi*hi + hi*lo + lo*hi (lo*lo ~2^-18, dropped)
    acc0 = __builtin_amdgcn_mfma_f32_32x32x16_bf16(ah, vh0, acc0, 0, 0, 0);
    acc1 = __builtin_amdgcn_mfma_f32_32x32x16_bf16(ah, vh1, acc1, 0, 0, 0);
    acc0 = __builtin_amdgcn_mfma_f32_32x32x16_bf16(ah, vl0, acc0, 0, 0, 0);
    acc1 = __builtin_amdgcn_mfma_f32_32x32x16_bf16(ah, vl1, acc1, 0, 0, 0);
    acc0 = __builtin_amdgcn_mfma_f32_32x32x16_bf16(al, vh0, acc0, 0, 0, 0);
    acc1 = __builtin_amdgcn_mfma_f32_32x32x16_bf16(al, vh1, acc1, 0, 0, 0);
  };

  ldxm(0, 0);
  ldw(0, 0); ldw(1, 1);

  for (int m = 0; m < NMAC; m += 2) {       // 2 macros/iter so slot ids stay literal
    if (m + 1 < NMAC) ldxm(m + 1, 1);       // next macro's burst in flight over compute
#pragma unroll
    for (int c = 0; c < 4; ++c) chunk(m * 4 + c, 0, c);
    if (m + 2 < NMAC) ldxm(m + 2, 0);
#pragma unroll
    for (int c = 0; c < 4; ++c) chunk((m + 1) * 4 + c, 1, c);
  }

  // dump partial tile to this wave's LDS slab.
  // C/D layout (m74/m101): expert col = lane&31, token row = (r&3)+8*(r>>2)+4*(lane>>5)
  {
    float* rp = &red[w][0];
#pragma unroll
    for (int r = 0; r < 16; ++r) {
      const int rr = (r & 3) + 8 * (r >> 2) + 4 * g;
      rp[rr * NEXP + row]      = acc0[r];   // banks: col%32, 2-way -> free
      rp[rr * NEXP + 32 + row] = acc1[r];
    }
  }
  __syncthreads();

  // reduce 4 K-quarters + bias. thread owns f = tid + 256*j (bank = tid%32, conflict-free;
  // expert index of f is tid&63 since 256*j is a multiple of 64)
  const float bias = b[tid & 63];
#pragma unroll
  for (int j = 0; j < 8; ++j) {
    const int f = tid + 256 * j;
    float s = red[0][f] + red[1][f] + red[2][f] + red[3][f] + bias;
    red[0][f] = s;                           // owner-exclusive, no race
  }
  __syncthreads();

  // top-2 + softmax: wave w handles tokens w*8 .. w*8+7, lane = expert
#pragma unroll
  for (int i = 0; i < 8; ++i) {
    const int tl = w * 8 + i;
    const float v = red[0][tl * NEXP + l];

    float m1 = v; int i1 = l;
#pragma unroll
    for (int off = 32; off > 0; off >>= 1) {
      float ov = __shfl_xor(m1, off, 64);
      int   oi = __shfl_xor(i1, off, 64);
      if (ov > m1 || (ov == m1 && oi < i1)) { m1 = ov; i1 = oi; }
    }
    float v2 = (l == i1) ? -__builtin_inff() : v;
    float m2 = v2; int i2 = l;
#pragma unroll
    for (int off = 32; off > 0; off >>= 1) {
      float ov = __shfl_xor(m2, off, 64);
      int   oi = __shfl_xor(i2, off, 64);
      if (ov > m2 || (ov == m2 && oi < i2)) { m2 = ov; i2 = oi; }
    }
    float e = __expf(v - m1);
#pragma unroll
    for (int off = 32; off > 0; off >>= 1) e += __shfl_xor(e, off, 64);

    if (l == 0) {
      const int t = t0 + tl;
      out[(size_t)t * 2 + 0] = (float)i1;
      out[(size_t)t * 2 + 1] = (float)i2;
      float inv = 1.0f / e;
      out[(size_t)TOKENS * 2 + (size_t)t * 2 + 0] = inv;
      out[(size_t)TOKENS * 2 + (size_t)t * 2 + 1] = __expf(m2 - m1) * inv;
    }
  }
}

extern "C" void kernel_launch(void* const* d_in, const int* in_sizes, int n_in,
                              void* d_out, int out_size, void* d_ws, size_t ws_size,
                              hipStream_t stream) {
  const float* x = (const float*)d_in[0];
  const float* W = (const float*)d_in[1];
  const float* b = (const float*)d_in[2];
  float* out = (float*)d_out;

  uint4* wh = (uint4*)d_ws;          // 32768 slots * 16B = 512 KB
  uint4* wl = wh + 32768;            // 512 KB

  hipLaunchKernelGGL(prep_W,    dim3(128),         dim3(256), 0, stream, W, wh, wl);
  hipLaunchKernelGGL(gemm_topk, dim3(TOKENS / 32), dim3(256), 0, stream, x, wh, wl, b, out);
}

// Round 11
// 74.865 us; speedup vs baseline: 1.1519x; 1.0380x over previous
//
#include <hip/hip_runtime.h>
#include <hip/hip_bf16.h>
#include <cstdint>
#include <cstddef>

#define TOKENS 16384
#define DMODEL 4096
#define NEXP   64
#define NWAVE  8                      // waves per block = K-split within block
#define KSPAN  (DMODEL / NWAVE)       // 512 k per wave
#define NKC    (KSPAN / 16)           // 32 k16-chunks per wave
#define NMAC   (NKC / 2)              // 16 macro-iters (2 chunks = 128B/row burst)

typedef __attribute__((ext_vector_type(8)))  short bf16x8;   // 8 bf16 = 4 VGPRs
typedef __attribute__((ext_vector_type(16))) float f32x16;   // 32x32 acc

// 8 fp32 -> hi/lo bf16 fragments (RNE hi, exact fp32 residual -> lo; ~2^-17 rel)
__device__ __forceinline__ void cvt_hilo8(const float f[8], bf16x8* hi, bf16x8* lo) {
  union { __hip_bfloat16 b; unsigned short u; } cv;
  bf16x8 hv, lv;
#pragma unroll
  for (int j = 0; j < 8; ++j) {
    __hip_bfloat16 hb = __float2bfloat16(f[j]);
    cv.b = hb; hv[j] = (short)cv.u;
    float r = f[j] - __bfloat162float(hb);          // exact
    cv.b = __float2bfloat16(r); lv[j] = (short)cv.u;
  }
  *hi = hv; *lo = lv;
}

// ---------------- kernel 1: W -> 32x32x16 B-fragments, bf16 hi/lo (verified) ----------
// slot (kc*2+et)*64+l <- B[k=kc*16+(l>>5)*8+j][e=et*32+(l&31)] = W[e][k+j]
__global__ __launch_bounds__(256)
void prep_W(const float* __restrict__ W, uint4* __restrict__ wh, uint4* __restrict__ wl) {
  const int tid = blockIdx.x * 256 + threadIdx.x;   // 32768 threads total
  const int l  = tid & 63;
  const int et = (tid >> 6) & 1;
  const int kc = tid >> 7;                           // 0..255 (global k16-chunk)
  const int e  = et * 32 + (l & 31);
  const int k  = kc * 16 + (l >> 5) * 8;
  const float* src = W + (size_t)e * DMODEL + k;
  float f[8];
#pragma unroll
  for (int j = 0; j < 8; ++j) f[j] = src[j];
  bf16x8 hi, lo;
  cvt_hilo8(f, &hi, &lo);
  const int slot = (kc * 2 + et) * 64 + l;
  wh[slot] = __builtin_bit_cast(uint4, hi);
  wl[slot] = __builtin_bit_cast(uint4, lo);
}

// ---------------- kernel 2: tile-pair GEMM (W read once per 64 tokens) + epilogue ------
// grid 256 x 512 thr (8 waves, 1 block/CU, 2 waves/SIMD). Block = 64 tokens; wave w =
// K-eighth w for tileA (t0..+31) AND tileB (t0+32..+63) -- each W chunk loaded from L2
// once and MFMA'd against both tiles (halves W L2 traffic vs R4).
__global__ __launch_bounds__(512, 2)
void gemm_topk(const float* __restrict__ x, const uint4* __restrict__ wh,
               const uint4* __restrict__ wl, const float* __restrict__ b,
               float* __restrict__ out) {
  __shared__ float red[NWAVE][64 * NEXP];   // 128 KB

  const int tid = threadIdx.x;
  const int l   = tid & 63;
  const int w   = tid >> 6;                 // wave id = K-eighth
  const int t0  = blockIdx.x * 64;
  const int row = l & 31, g = l >> 5;

  const float* xpA = x + (size_t)(t0 + row) * DMODEL + w * KSPAN + g * 8;
  const float* xpB = xpA + (size_t)32 * DMODEL;
  const uint4* whp = wh + (size_t)w * (NKC * 128) + l;   // 128 uint4 per k16-chunk
  const uint4* wlp = wl + (size_t)w * (NKC * 128) + l;

  f32x16 accA0, accA1, accB0, accB1;
#pragma unroll
  for (int i = 0; i < 16; ++i) { accA0[i] = 0.f; accA1[i] = 0.f; accB0[i] = 0.f; accB1[i] = 0.f; }

  // x: macro (2 chunks x 2 tiles = 8 float4) double-buffered; W: depth-2 chunk rotation.
  float4 xa[2][8];
  uint4  ph0[2], ph1[2], pl0[2], pl1[2];

  auto ldxm = [&](int mac, int s) {          // 128B/row bursts, tileA rows then tileB rows
#pragma unroll
    for (int c = 0; c < 2; ++c) {
      const float* xn = xpA + (size_t)(mac * 2 + c) * 16;
      xa[s][c * 2]     = *(const float4*)(xn);
      xa[s][c * 2 + 1] = *(const float4*)(xn + 4);
    }
#pragma unroll
    for (int c = 0; c < 2; ++c) {
      const float* xn = xpB + (size_t)(mac * 2 + c) * 16;
      xa[s][4 + c * 2]     = *(const float4*)(xn);
      xa[s][4 + c * 2 + 1] = *(const float4*)(xn + 4);
    }
  };
  auto ldw = [&](int kc, int s) {
    ph0[s] = whp[(size_t)kc * 128];  ph1[s] = whp[(size_t)kc * 128 + 64];
    pl0[s] = wlp[(size_t)kc * 128];  pl1[s] = wlp[(size_t)kc * 128 + 64];
  };

  auto chunk = [&](int kc, int xs, int c) {  // one W chunk -> both tiles (12 MFMA)
    const int ws = kc & 1;
    float4 aA0 = xa[xs][c * 2],     aA1 = xa[xs][c * 2 + 1];
    float4 aB0 = xa[xs][4 + c * 2], aB1 = xa[xs][4 + c * 2 + 1];
    uint4 bh0 = ph0[ws], bh1 = ph1[ws], bl0 = pl0[ws], bl1 = pl1[ws];
    if (kc + 2 < NKC) ldw(kc + 2, ws);       // same parity -> same slot, freed this chunk
    float fA[8] = {aA0.x, aA0.y, aA0.z, aA0.w, aA1.x, aA1.y, aA1.z, aA1.w};
    float fB[8] = {aB0.x, aB0.y, aB0.z, aB0.w, aB1.x, aB1.y, aB1.z, aB1.w};
    bf16x8 ahA, alA, ahB, alB;
    cvt_hilo8(fA, &ahA, &alA);
    cvt_hilo8(fB, &ahB, &alB);
    bf16x8 vh0 = __builtin_bit_cast(bf16x8, bh0);
    bf16x8 vh1 = __builtin_bit_cast(bf16x8, bh1);
    bf16x8 vl0 = __builtin_bit_cast(bf16x8, bl0);
    bf16x8 vl1 = __builtin_bit_cast(bf16x8, bl1);
    // fp32-emulated: hi*hi + hi*lo + lo*hi (lo*lo ~2^-18, dropped)
    accA0 = __builtin_amdgcn_mfma_f32_32x32x16_bf16(ahA, vh0, accA0, 0, 0, 0);
    accA1 = __builtin_amdgcn_mfma_f32_32x32x16_bf16(ahA, vh1, accA1, 0, 0, 0);
    accB0 = __builtin_amdgcn_mfma_f32_32x32x16_bf16(ahB, vh0, accB0, 0, 0, 0);
    accB1 = __builtin_amdgcn_mfma_f32_32x32x16_bf16(ahB, vh1, accB1, 0, 0, 0);
    accA0 = __builtin_amdgcn_mfma_f32_32x32x16_bf16(ahA, vl0, accA0, 0, 0, 0);
    accA1 = __builtin_amdgcn_mfma_f32_32x32x16_bf16(ahA, vl1, accA1, 0, 0, 0);
    accB0 = __builtin_amdgcn_mfma_f32_32x32x16_bf16(ahB, vl0, accB0, 0, 0, 0);
    accB1 = __builtin_amdgcn_mfma_f32_32x32x16_bf16(ahB, vl1, accB1, 0, 0, 0);
    accA0 = __builtin_amdgcn_mfma_f32_32x32x16_bf16(alA, vh0, accA0, 0, 0, 0);
    accA1 = __builtin_amdgcn_mfma_f32_32x32x16_bf16(alA, vh1, accA1, 0, 0, 0);
    accB0 = __builtin_amdgcn_mfma_f32_32x32x16_bf16(alB, vh0, accB0, 0, 0, 0);
    accB1 = __builtin_amdgcn_mfma_f32_32x32x16_bf16(alB, vh1, accB1, 0, 0, 0);
  };

  ldxm(0, 0);
  ldw(0, 0); ldw(1, 1);

  for (int m = 0; m < NMAC; m += 2) {        // 2 macros/iter so slot ids stay literal
    if (m + 1 < NMAC) ldxm(m + 1, 1);        // next macro's bursts in flight over compute
    chunk(m * 2, 0, 0);  chunk(m * 2 + 1, 0, 1);
    if (m + 2 < NMAC) ldxm(m + 2, 0);
    chunk((m + 1) * 2, 1, 0);  chunk((m + 1) * 2 + 1, 1, 1);
  }

  // dump partials. C/D layout: expert col = lane&31, token row rr = (r&3)+8*(r>>2)+4*g
  {
    float* rp = &red[w][0];
#pragma unroll
    for (int r = 0; r < 16; ++r) {
      const int rr = (r & 3) + 8 * (r >> 2) + 4 * g;
      rp[rr * NEXP + row]             = accA0[r];   // 2-way bank alias -> free
      rp[rr * NEXP + 32 + row]        = accA1[r];
      rp[(32 + rr) * NEXP + row]      = accB0[r];
      rp[(32 + rr) * NEXP + 32 + row] = accB1[r];
    }
  }
  __syncthreads();

  // reduce 8 K-eighths + bias. thread owns f = tid + 512*j (bank tid%32, conflict-free;
  // expert index of f is tid&63 since 512*j is a multiple of 64)
  const float bias = b[tid & 63];
#pragma unroll
  for (int j = 0; j < 8; ++j) {
    const int f = tid + 512 * j;
    float s = red[0][f] + red[1][f] + red[2][f] + red[3][f]
            + red[4][f] + red[5][f] + red[6][f] + red[7][f] + bias;
    red[0][f] = s;                           // owner-exclusive, no race
  }
  __syncthreads();

  // top-2 + softmax: wave w handles tokens w*8 .. w*8+7, lane = expert
#pragma unroll
  for (int i = 0; i < 8; ++i) {
    const int tl = w * 8 + i;
    const float v = red[0][tl * NEXP + l];

    float m1 = v; int i1 = l;
#pragma unroll
    for (int off = 32; off > 0; off >>= 1) {
      float ov = __shfl_xor(m1, off, 64);
      int   oi = __shfl_xor(i1, off, 64);
      if (ov > m1 || (ov == m1 && oi < i1)) { m1 = ov; i1 = oi; }
    }
    float v2 = (l == i1) ? -__builtin_inff() : v;
    float m2 = v2; int i2 = l;
#pragma unroll
    for (int off = 32; off > 0; off >>= 1) {
      float ov = __shfl_xor(m2, off, 64);
      int   oi = __shfl_xor(i2, off, 64);
      if (ov > m2 || (ov == m2 && oi < i2)) { m2 = ov; i2 = oi; }
    }
    float e = __expf(v - m1);
#pragma unroll
    for (int off = 32; off > 0; off >>= 1) e += __shfl_xor(e, off, 64);

    if (l == 0) {
      const int t = t0 + tl;
      out[(size_t)t * 2 + 0] = (float)i1;
      out[(size_t)t * 2 + 1] = (float)i2;
      float inv = 1.0f / e;
      out[(size_t)TOKENS * 2 + (size_t)t * 2 + 0] = inv;
      out[(size_t)TOKENS * 2 + (size_t)t * 2 + 1] = __expf(m2 - m1) * inv;
    }
  }
}

extern "C" void kernel_launch(void* const* d_in, const int* in_sizes, int n_in,
                              void* d_out, int out_size, void* d_ws, size_t ws_size,
                              hipStream_t stream) {
  const float* x = (const float*)d_in[0];
  const float* W = (const float*)d_in[1];
  const float* b = (const float*)d_in[2];
  float* out = (float*)d_out;

  uint4* wh = (uint4*)d_ws;          // 32768 slots * 16B = 512 KB
  uint4* wl = wh + 32768;            // 512 KB

  hipLaunchKernelGGL(prep_W,    dim3(128),         dim3(256), 0, stream, W, wh, wl);
  hipLaunchKernelGGL(gemm_topk, dim3(TOKENS / 64), dim3(512), 0, stream, x, wh, wl, b, out);
}